// Round 2
// baseline (411.138 us; speedup 1.0000x reference)
//
#include <hip/hip_runtime.h>
#include <math.h>

// Problem constants (match reference setup_inputs)
constexpr int kB  = 8;
constexpr int kA  = 100000;
constexpr int kM  = 100;
constexpr int kCH = 85;          // 5 + NCLS
constexpr float kEPS = 1e-4f;

constexpr int kA4   = kA / 4;                // 25000 float4 per channel row
constexpr int kGX   = (kA4 + 255) / 256;     // 98 producer blocks in x
constexpr int kNBLK = kGX * kB;              // 784 producer blocks total

// log(EPS), log(1-EPS) in fp32
#define L0 (-9.210340371976182f)
#define L1 (-1.0000500033334732e-4f)

__device__ __forceinline__ float clipf(float x) {
    return fminf(fmaxf(x, kEPS), 1.0f - kEPS);
}

__device__ __forceinline__ float wave_reduce_f(float v) {
#pragma unroll
    for (int off = 32; off > 0; off >>= 1) v += __shfl_down(v, off, 64);
    return v;
}

// ws layout:
//   float4 partials[kNBLK]   (per-block {cls_sum, box_sum, n_cls, n_box})
//   int    flags[kNBLK]      (0xAAAAAAAA poison -> 1 when partial published)
// The harness re-poisons ws with 0xAA before every call, so flags start != 1.
// Producer blocks publish partials with agent-scope atomics (cross-XCD safe),
// then release-store their flag. The single finalizer block (last in dispatch
// order) acquire-polls all flags, reduces, and writes out[0]. No deadlock:
// producers never wait on the finalizer; it occupies one CU slot only.
__global__ __launch_bounds__(256) void loss_fused(
    const float* __restrict__ dt, const float* __restrict__ gt,
    const float* __restrict__ anchors, const int* __restrict__ assign,
    float* __restrict__ ws, float* __restrict__ out)
{
    float* pf   = ws;                         // partials as 4 floats per slot
    int*   flags = (int*)(ws + 4 * (size_t)kNBLK);

    // ---------------- finalizer block ----------------
    if (blockIdx.x == kGX) {
        if (blockIdx.y != kB - 1) return;     // 7 idle blocks exit immediately

        // wait for all producer partials
        for (int i = threadIdx.x; i < kNBLK; i += 256) {
            while (__hip_atomic_load(&flags[i], __ATOMIC_ACQUIRE,
                                     __HIP_MEMORY_SCOPE_AGENT) != 1) { }
        }
        __syncthreads();

        // 4 waves x 2 batches each
        __shared__ float s_loss[kB];
        const int lane = threadIdx.x & 63, wid = threadIdx.x >> 6;
#pragma unroll
        for (int k = 0; k < 2; ++k) {
            const int b = wid * 2 + k;
            float cls = 0.f, box = 0.f, nc = 0.f, nb = 0.f;
            for (int e = lane; e < kGX; e += 64) {
                float* p = pf + 4 * ((size_t)b * kGX + e);
                cls += __hip_atomic_load(&p[0], __ATOMIC_RELAXED, __HIP_MEMORY_SCOPE_AGENT);
                box += __hip_atomic_load(&p[1], __ATOMIC_RELAXED, __HIP_MEMORY_SCOPE_AGENT);
                nc  += __hip_atomic_load(&p[2], __ATOMIC_RELAXED, __HIP_MEMORY_SCOPE_AGENT);
                nb  += __hip_atomic_load(&p[3], __ATOMIC_RELAXED, __HIP_MEMORY_SCOPE_AGENT);
            }
            cls = wave_reduce_f(cls);
            box = wave_reduce_f(box);
            nc  = wave_reduce_f(nc);
            nb  = wave_reduce_f(nb);
            if (lane == 0) {
                const float cl = cls / fmaxf(nc, 1.0f);
                const float bl = (nb > 0.f) ? box / fmaxf(nb, 1.0f) : 0.f;
                s_loss[b] = cl + bl;
            }
        }
        __syncthreads();
        if (threadIdx.x == 0) {
            float tot = 0.f;
#pragma unroll
            for (int bb = 0; bb < kB; ++bb) tot += s_loss[bb];
            out[0] = tot / (float)kB;
        }
        return;
    }

    // ---------------- producer blocks ----------------
    const int b = blockIdx.y;
    const int i = blockIdx.x * 256 + threadIdx.x;   // float4 index along A

    float cls_c = 0.f, box_c = 0.f, ncls_c = 0.f, nbox_c = 0.f;

    if (i < kA4) {
        // 16B/lane loads everywhere on the streaming path
        const int4 as4 = ((const int4*)(assign + (size_t)b * kA))[i];
        const int as[4] = {as4.x, as4.y, as4.z, as4.w};

        const float4* dp4 = (const float4*)(dt + (size_t)b * kCH * kA) + i;

        // box channels 0..3 (issued early so they're in flight)
        const float4 d0 = dp4[0];
        const float4 d1 = dp4[(size_t)1 * kA4];
        const float4 d2 = dp4[(size_t)2 * kA4];
        const float4 d3 = dp4[(size_t)3 * kA4];

        // objectness channel (c = 4)
        const float4 v4 = dp4[(size_t)4 * kA4];
        const float pobj[4] = {clipf(v4.x), clipf(v4.y), clipf(v4.z), clipf(v4.w)};
        float P[4] = {pobj[0], pobj[1], pobj[2], pobj[3]};

        // class channels 5..84 (80 iterations)
#pragma unroll 10
        for (int c = 5; c < kCH; ++c) {
            const float4 u = dp4[(size_t)c * kA4];
            P[0] += clipf(u.x);
            P[1] += clipf(u.y);
            P[2] += clipf(u.z);
            P[3] += clipf(u.w);
        }

        const float d0a[4] = {d0.x, d0.y, d0.z, d0.w};
        const float d1a[4] = {d1.x, d1.y, d1.z, d1.w};
        const float d2a[4] = {d2.x, d2.y, d2.z, d2.w};
        const float d3a[4] = {d3.x, d3.y, d3.z, d3.w};

#pragma unroll
        for (int j = 0; j < 4; ++j) {
            const int as_j = as[j];
            if (as_j < 0) continue;                   // ignore
            // background contribution: all 81 targets clipped to EPS
            float per = (L1 - L0) * P[j] - 81.0f * L1;
            if (as_j >= 1) {                          // assigned to a gt box
                const int idx = min(as_j - 1, kM - 1);
                const float* g = gt + ((size_t)b * kM + idx) * 5;
                const float g0 = g[0], g1 = g[1], g2 = g[2], g3 = g[3];
                const int cls = (int)g[4];            // 1..NCLS

                // correction for the two channels whose target is 1-EPS
                const float p_cls =
                    clipf(dt[((size_t)b * kCH + 4 + cls) * kA + 4 * i + j]);
                per += (2.0f * (pobj[j] + p_cls) - 2.0f) * (L0 - L1);

                // box regression
                const float4 av = ((const float4*)anchors)[4 * i + j];
                const float aw = av.z - av.x, ah = av.w - av.y;
                const float ax = av.x + 0.5f * aw, ay = av.y + 0.5f * ah;
                const float t0 = (g0 + 0.5f * g2 - ax) / aw - d0a[j];
                const float t1 = (g1 + 0.5f * g3 - ay) / ah - d1a[j];
                const float t2 = logf(g2 / aw) - d2a[j];
                const float t3 = logf(g3 / ah) - d3a[j];
                box_c += t0 * t0 + t1 * t1 + t2 * t2 + t3 * t3;
                nbox_c += 1.f;
            }
            cls_c += per;
            ncls_c += 1.f;
        }
    }

    // block reduction: wave shuffle -> LDS across 4 waves -> publish
    cls_c  = wave_reduce_f(cls_c);
    box_c  = wave_reduce_f(box_c);
    ncls_c = wave_reduce_f(ncls_c);
    nbox_c = wave_reduce_f(nbox_c);

    __shared__ float4 s[4];
    const int lane = threadIdx.x & 63, wid = threadIdx.x >> 6;
    if (lane == 0) s[wid] = make_float4(cls_c, box_c, ncls_c, nbox_c);
    __syncthreads();
    if (threadIdx.x == 0) {
        float4 t = s[0];
#pragma unroll
        for (int w = 1; w < 4; ++w) {
            t.x += s[w].x; t.y += s[w].y; t.z += s[w].z; t.w += s[w].w;
        }
        const int slot = b * kGX + blockIdx.x;
        float* p = pf + 4 * (size_t)slot;
        __hip_atomic_store(&p[0], t.x, __ATOMIC_RELAXED, __HIP_MEMORY_SCOPE_AGENT);
        __hip_atomic_store(&p[1], t.y, __ATOMIC_RELAXED, __HIP_MEMORY_SCOPE_AGENT);
        __hip_atomic_store(&p[2], t.z, __ATOMIC_RELAXED, __HIP_MEMORY_SCOPE_AGENT);
        __hip_atomic_store(&p[3], t.w, __ATOMIC_RELAXED, __HIP_MEMORY_SCOPE_AGENT);
        __hip_atomic_store(&flags[slot], 1, __ATOMIC_RELEASE, __HIP_MEMORY_SCOPE_AGENT);
    }
}

extern "C" void kernel_launch(void* const* d_in, const int* in_sizes, int n_in,
                              void* d_out, int out_size, void* d_ws, size_t ws_size,
                              hipStream_t stream) {
    const float* dt      = (const float*)d_in[0];   // [B, 85, A] fp32
    const float* gt      = (const float*)d_in[1];   // [B, M, 5] fp32
    const float* anchors = (const float*)d_in[2];   // [A, 4] fp32
    const int*   assign  = (const int*)d_in[3];     // [B, A] int32
    float* out = (float*)d_out;

    dim3 grid(kGX + 1, kB);   // +1 column: finalizer block at (kGX, kB-1)
    loss_fused<<<grid, 256, 0, stream>>>(dt, gt, anchors, assign,
                                         (float*)d_ws, out);
}

// Round 3
// 382.575 us; speedup vs baseline: 1.0747x; 1.0747x over previous
//
#include <hip/hip_runtime.h>
#include <math.h>

// Problem constants (match reference setup_inputs)
constexpr int kB  = 8;
constexpr int kA  = 100000;
constexpr int kM  = 100;
constexpr int kCH = 85;          // 5 + NCLS
constexpr float kEPS = 1e-4f;

constexpr int kA4 = kA / 4;                 // 25000 float4 per channel row
constexpr int kGX = (kA4 + 255) / 256;      // 98 blocks in x

// log(EPS), log(1-EPS) in fp32
#define L0 (-9.210340371976182f)
#define L1 (-1.0000500033334732e-4f)

__device__ __forceinline__ float clipf(float x) {
    return fminf(fmaxf(x, kEPS), 1.0f - kEPS);
}

__device__ __forceinline__ float wave_reduce_f(float v) {
#pragma unroll
    for (int off = 32; off > 0; off >>= 1) v += __shfl_down(v, off, 64);
    return v;
}

// Each block writes ONE float4 partial {cls_sum, box_sum, n_cls, n_box} to
// ws[b * kGX + blockIdx.x]. Every slot is written unconditionally, so the
// poisoned workspace needs no memset. Counts fit exactly in fp32 (<= 1e5).
__global__ __launch_bounds__(256) void loss_main(
    const float* __restrict__ dt, const float* __restrict__ gt,
    const float* __restrict__ anchors, const int* __restrict__ assign,
    float4* __restrict__ partials)
{
    const int b = blockIdx.y;
    const int i = blockIdx.x * 256 + threadIdx.x;   // float4 index along A

    float cls_c = 0.f, box_c = 0.f, ncls_c = 0.f, nbox_c = 0.f;

    if (i < kA4) {
        // 16B/lane loads everywhere on the streaming path
        const int4 as4 = ((const int4*)(assign + (size_t)b * kA))[i];
        const int as[4] = {as4.x, as4.y, as4.z, as4.w};

        const float4* dp4 = (const float4*)(dt + (size_t)b * kCH * kA) + i;

        // box channels 0..3 (issued early so they're in flight)
        const float4 d0 = dp4[0];
        const float4 d1 = dp4[(size_t)1 * kA4];
        const float4 d2 = dp4[(size_t)2 * kA4];
        const float4 d3 = dp4[(size_t)3 * kA4];

        // objectness channel (c = 4)
        const float4 v4 = dp4[(size_t)4 * kA4];
        const float pobj[4] = {clipf(v4.x), clipf(v4.y), clipf(v4.z), clipf(v4.w)};
        float P[4] = {pobj[0], pobj[1], pobj[2], pobj[3]};

        // class channels 5..84 (80 iterations)
#pragma unroll 10
        for (int c = 5; c < kCH; ++c) {
            const float4 u = dp4[(size_t)c * kA4];
            P[0] += clipf(u.x);
            P[1] += clipf(u.y);
            P[2] += clipf(u.z);
            P[3] += clipf(u.w);
        }

        const float d0a[4] = {d0.x, d0.y, d0.z, d0.w};
        const float d1a[4] = {d1.x, d1.y, d1.z, d1.w};
        const float d2a[4] = {d2.x, d2.y, d2.z, d2.w};
        const float d3a[4] = {d3.x, d3.y, d3.z, d3.w};

#pragma unroll
        for (int j = 0; j < 4; ++j) {
            const int as_j = as[j];
            if (as_j < 0) continue;                   // ignore
            // background contribution: all 81 targets clipped to EPS
            float per = (L1 - L0) * P[j] - 81.0f * L1;
            if (as_j >= 1) {                          // assigned to a gt box
                const int idx = min(as_j - 1, kM - 1);
                const float* g = gt + ((size_t)b * kM + idx) * 5;
                const float g0 = g[0], g1 = g[1], g2 = g[2], g3 = g[3];
                const int cls = (int)g[4];            // 1..NCLS

                // correction for the two channels whose target is 1-EPS
                const float p_cls =
                    clipf(dt[((size_t)b * kCH + 4 + cls) * kA + 4 * i + j]);
                per += (2.0f * (pobj[j] + p_cls) - 2.0f) * (L0 - L1);

                // box regression
                const float4 av = ((const float4*)anchors)[4 * i + j];
                const float aw = av.z - av.x, ah = av.w - av.y;
                const float ax = av.x + 0.5f * aw, ay = av.y + 0.5f * ah;
                const float t0 = (g0 + 0.5f * g2 - ax) / aw - d0a[j];
                const float t1 = (g1 + 0.5f * g3 - ay) / ah - d1a[j];
                const float t2 = logf(g2 / aw) - d2a[j];
                const float t3 = logf(g3 / ah) - d3a[j];
                box_c += t0 * t0 + t1 * t1 + t2 * t2 + t3 * t3;
                nbox_c += 1.f;
            }
            cls_c += per;
            ncls_c += 1.f;
        }
    }

    // block reduction: wave shuffle -> LDS across 4 waves -> one store
    cls_c  = wave_reduce_f(cls_c);
    box_c  = wave_reduce_f(box_c);
    ncls_c = wave_reduce_f(ncls_c);
    nbox_c = wave_reduce_f(nbox_c);

    __shared__ float4 s[4];
    const int lane = threadIdx.x & 63, wid = threadIdx.x >> 6;
    if (lane == 0) s[wid] = make_float4(cls_c, box_c, ncls_c, nbox_c);
    __syncthreads();
    if (threadIdx.x == 0) {
        float4 t = s[0];
#pragma unroll
        for (int w = 1; w < 4; ++w) {
            t.x += s[w].x; t.y += s[w].y; t.z += s[w].z; t.w += s[w].w;
        }
        partials[(size_t)b * kGX + blockIdx.x] = t;
    }
}

// 8 waves, one per batch element; each wave reduces its 98 partials.
__global__ __launch_bounds__(512) void loss_final(
    const float4* __restrict__ partials, float* __restrict__ out)
{
    const int wid  = threadIdx.x >> 6;    // = b (0..7)
    const int lane = threadIdx.x & 63;

    float cls = 0.f, box = 0.f, nc = 0.f, nb = 0.f;
    for (int e = lane; e < kGX; e += 64) {
        const float4 p = partials[(size_t)wid * kGX + e];
        cls += p.x; box += p.y; nc += p.z; nb += p.w;
    }
    cls = wave_reduce_f(cls);
    box = wave_reduce_f(box);
    nc  = wave_reduce_f(nc);
    nb  = wave_reduce_f(nb);

    __shared__ float s_loss[8];
    if (lane == 0) {
        const float cl = cls / fmaxf(nc, 1.0f);
        const float bl = (nb > 0.f) ? box / fmaxf(nb, 1.0f) : 0.f;
        s_loss[wid] = cl + bl;
    }
    __syncthreads();
    if (threadIdx.x == 0) {
        float tot = 0.f;
#pragma unroll
        for (int bb = 0; bb < kB; ++bb) tot += s_loss[bb];
        out[0] = tot / (float)kB;
    }
}

extern "C" void kernel_launch(void* const* d_in, const int* in_sizes, int n_in,
                              void* d_out, int out_size, void* d_ws, size_t ws_size,
                              hipStream_t stream) {
    const float* dt      = (const float*)d_in[0];   // [B, 85, A] fp32
    const float* gt      = (const float*)d_in[1];   // [B, M, 5] fp32
    const float* anchors = (const float*)d_in[2];   // [A, 4] fp32
    const int*   assign  = (const int*)d_in[3];     // [B, A] int32
    float* out = (float*)d_out;

    float4* partials = (float4*)d_ws;   // kB * kGX slots, all written every call

    dim3 grid(kGX, kB);
    loss_main<<<grid, 256, 0, stream>>>(dt, gt, anchors, assign, partials);
    loss_final<<<1, 512, 0, stream>>>(partials, out);
}